// Round 5
// baseline (95915.430 us; speedup 1.0000x reference)
//
#include <hip/hip_runtime.h>

// ODE_Vanilla scan: B=128, T=256, I=256, H=1024, C=10, fp32.
// R5: ONE persistent kernel for all 256 steps. Evidence: R1/R2/R4 all cost
// ~21-24us/dispatch regardless of body => fixed dispatch overhead dominated.
// R3 showed per-block __threadfence barriers wipe L2 (66GB HBM/step). Here:
// - h/v exchange goes through MALL (L3, cross-XCD coherent) via inline-asm
//   sc0 sc1 loads/stores -> NO fences, weights stay L2-resident forever.
// - sync: per-rt-group (64 blocks) arrival counters, device-scope atomicAdd
//   (executes at MALL) + relaxed polls. Rows never interact across groups.
// - compute core: R4's verified 16x16 block tile, lane=64-way k-split,
//   8x8 register tiles, reduce-scatter butterfly. 512 blocks = 2/CU resident.

constexpr int Bsz = 128, Tn = 256, In = 256, Hn = 1024, Cn = 10;
constexpr float LR = 0.001f;

// ---- pack Wh, Wx into [ct][k][16 cols] contiguous slices
__global__ __launch_bounds__(256) void k_pack(const float* __restrict__ Wh,
                                              const float* __restrict__ Wx,
                                              float* __restrict__ Whp,
                                              float* __restrict__ Wxp) {
  const int g = blockIdx.x * 256 + threadIdx.x;
  {
    const int k = g >> 10, c = g & 1023;
    Whp[(((size_t)(c >> 4) * Hn + k) << 4) + (c & 15)] = Wh[g];
  }
  if (g < In * Hn) {
    const int k = g >> 10, c = g & 1023;
    Wxp[(((size_t)(c >> 4) * In + k) << 4) + (c & 15)] = Wx[g];
  }
}

// ---- Wh^T packed into [ct][k][16 cols]
__global__ __launch_bounds__(256) void k_transpack(const float* __restrict__ W,
                                                   float* __restrict__ WTp) {
  __shared__ float tile[32][33];
  const int bx = blockIdx.x * 32, by = blockIdx.y * 32;
  const int tx = threadIdx.x & 31, ty = threadIdx.x >> 5;
#pragma unroll
  for (int dy = 0; dy < 32; dy += 8)
    tile[ty + dy][tx] = W[(size_t)(by + ty + dy) * Hn + bx + tx];
  __syncthreads();
#pragma unroll
  for (int dy = 0; dy < 32; dy += 8) {
    const int k = bx + ty + dy, c = by + tx;
    WTp[(((size_t)(c >> 4) * Hn + k) << 4) + (c & 15)] = tile[tx][ty + dy];
  }
}

__global__ __launch_bounds__(256) void k_init(float* __restrict__ out,
                                              const float* __restrict__ fc_b,
                                              float* __restrict__ h_cur,
                                              const float* __restrict__ hidden,
                                              int* __restrict__ flags) {
  const int i = blockIdx.x * blockDim.x + threadIdx.x;
  if (i < Bsz * Tn * Cn) out[i] = fc_b[i % Cn];
  if (i < Bsz * Hn) h_cur[i] = hidden[i];
  if (i < Tn * 16) flags[i] = 0;
}

// ---- MALL-coherent (cross-XCD) access helpers: bypass L1+L2 via sc0 sc1
__device__ __forceinline__ void ldx8_sc01(const float4* b, float4 (&r)[8]) {
  asm volatile(
      "global_load_dwordx4 %0, %8, off sc0 sc1\n\t"
      "global_load_dwordx4 %1, %9, off sc0 sc1\n\t"
      "global_load_dwordx4 %2, %10, off sc0 sc1\n\t"
      "global_load_dwordx4 %3, %11, off sc0 sc1\n\t"
      "global_load_dwordx4 %4, %12, off sc0 sc1\n\t"
      "global_load_dwordx4 %5, %13, off sc0 sc1\n\t"
      "global_load_dwordx4 %6, %14, off sc0 sc1\n\t"
      "global_load_dwordx4 %7, %15, off sc0 sc1\n\t"
      "s_waitcnt vmcnt(0)"
      : "=&v"(r[0]), "=&v"(r[1]), "=&v"(r[2]), "=&v"(r[3]),
        "=&v"(r[4]), "=&v"(r[5]), "=&v"(r[6]), "=&v"(r[7])
      : "v"(b), "v"(b + 256), "v"(b + 512), "v"(b + 768),
        "v"(b + 1024), "v"(b + 1280), "v"(b + 1536), "v"(b + 1792)
      : "memory");
}
__device__ __forceinline__ void st_f32_sc01(float* p, float v) {
  asm volatile("global_store_dword %0, %1, off sc0 sc1" ::"v"(p), "v"(v)
               : "memory");
}
__device__ __forceinline__ void vm_wait0() {
  asm volatile("s_waitcnt vmcnt(0)" ::: "memory");
}

// ---- group barrier: 64 blocks arrive on one counter; no fences (data went
// through MALL already). Bounded spin = visible failure instead of a hang.
__device__ __forceinline__ void group_barrier(int* flag) {
  __syncthreads();
  if (threadIdx.x == 0) {
    __hip_atomic_fetch_add(flag, 1, __ATOMIC_RELAXED, __HIP_MEMORY_SCOPE_AGENT);
    int iter = 0;
    while (__hip_atomic_load(flag, __ATOMIC_RELAXED,
                             __HIP_MEMORY_SCOPE_AGENT) < 64) {
      __builtin_amdgcn_s_sleep(1);
      if (++iter > 2000000) break;  // escape hatch
    }
  }
  __syncthreads();
}

// reduce-scatter over 64 lanes: lane l ends with full sum of a[l]
__device__ __forceinline__ float reduce_scatter64(float (&a)[64], int lane) {
#pragma unroll
  for (int m = 32; m >= 1; m >>= 1) {
#pragma unroll
    for (int i = 0; i < m; i++) {
      const float send = (lane & m) ? a[i] : a[i + m];
      const float keep = (lane & m) ? a[i + m] : a[i];
      a[i] = keep + __shfl_xor(send, m, 64);
    }
  }
  return a[0];
}

#define FMA8(s, wA, wB, base)                          \
  a[(base) + 0] = fmaf((s), (wA).x, a[(base) + 0]);    \
  a[(base) + 1] = fmaf((s), (wA).y, a[(base) + 1]);    \
  a[(base) + 2] = fmaf((s), (wA).z, a[(base) + 2]);    \
  a[(base) + 3] = fmaf((s), (wA).w, a[(base) + 3]);    \
  a[(base) + 4] = fmaf((s), (wB).x, a[(base) + 4]);    \
  a[(base) + 5] = fmaf((s), (wB).y, a[(base) + 5]);    \
  a[(base) + 6] = fmaf((s), (wB).z, a[(base) + 6]);    \
  a[(base) + 7] = fmaf((s), (wB).w, a[(base) + 7]);

// grid 512 = rt(8) x ct(64); 256 thr = 4 waves; lane = 64-way k-split.
// Thread owns output element (rg0 + r0w + (lane>>3), c_blk + c0w + (lane&7))
// for the whole scan: h kept in a register across steps.
__global__ __launch_bounds__(256, 2) void k_persist(
    const float* __restrict__ X, float* __restrict__ h_cur,
    float* __restrict__ v_buf, const float* __restrict__ Whp,
    const float* __restrict__ Wxp, const float* __restrict__ WTp,
    const float* __restrict__ bias, const float* __restrict__ alpha,
    const float* __restrict__ fc_w, float* __restrict__ out,
    float* __restrict__ hfin, int* __restrict__ flags) {
  extern __shared__ float sm[];  // 16 rows x 1024 = 64 KB
  __shared__ float hn_s[16][16];
  const int tid = threadIdx.x, lane = tid & 63, w = tid >> 6;
  const int rt = blockIdx.x >> 6, ct = blockIdx.x & 63;
  const int rg0 = rt * 16, c_blk = ct * 16;
  const int r0w = (w >> 1) * 8, c0w = (w & 1) * 8;
  const int rl = r0w + (lane >> 3), cl = c0w + (lane & 7);
  const int cg = c_blk + cl;
  const size_t hidx = (size_t)(rg0 + rl) * Hn + cg;
  const float av = alpha[0];
  const float b_own = bias[cg];
  float h_own = h_cur[hidx];  // initial h (k_init wrote it; dispatch-coherent)
  // preload FC weights for the reduction threads (t-invariant)
  float fc_r[16];
  const int rr = tid / 10, cc = tid % 10;
  if (tid < 160) {
#pragma unroll
    for (int jj = 0; jj < 16; jj++)
      fc_r[jj] = fc_w[(size_t)(c_blk + jj) * Cn + cc];
  }

  for (int t = 0; t < Tn; t++) {
    // ---- stage h rows via MALL-coherent loads ----
    {
      const float4* src = (const float4*)(h_cur + (size_t)rg0 * Hn) + tid;
      float4 r[8];
      float4* dst = (float4*)sm;
      ldx8_sc01(src, r);
#pragma unroll
      for (int u = 0; u < 8; u++) dst[tid + 256 * u] = r[u];
      ldx8_sc01(src + 2048, r);
#pragma unroll
      for (int u = 0; u < 8; u++) dst[tid + 2048 + 256 * u] = r[u];
    }
    __syncthreads();

    // ---- phase 1: pre = h@Wh + x@Wx ----
    float a[64];
#pragma unroll
    for (int i = 0; i < 64; i++) a[i] = 0.f;
    {
      const float* Wb = Whp + ((size_t)ct * Hn << 4) + c0w;
#pragma unroll
      for (int j = 0; j < 4; j++) {
        const int kb = 4 * lane + 256 * j;
        float4 h4[8];
#pragma unroll
        for (int i = 0; i < 8; i++)
          h4[i] = *(const float4*)(sm + (r0w + i) * Hn + kb);
#pragma unroll
        for (int q = 0; q < 4; q++) {
          const float* wr = Wb + ((size_t)(kb + q) << 4);
          const float4 wA = *(const float4*)(wr);
          const float4 wB = *(const float4*)(wr + 4);
#pragma unroll
          for (int i = 0; i < 8; i++) {
            const float hv = ((const float*)&h4[i])[q];
            FMA8(hv, wA, wB, i * 8);
          }
        }
      }
    }
    {
      const int kb = 4 * lane;
      float4 x4[8];
#pragma unroll
      for (int i = 0; i < 8; i++)
        x4[i] = *(const float4*)(X + ((size_t)(rg0 + r0w + i) * Tn + t) * In + kb);
      const float* Wb = Wxp + ((size_t)ct * In << 4) + c0w;
#pragma unroll
      for (int q = 0; q < 4; q++) {
        const float* wr = Wb + ((size_t)(kb + q) << 4);
        const float4 wA = *(const float4*)(wr);
        const float4 wB = *(const float4*)(wr + 4);
#pragma unroll
        for (int i = 0; i < 8; i++) {
          const float xv = ((const float*)&x4[i])[q];
          FMA8(xv, wA, wB, i * 8);
        }
      }
    }
    const float pre = reduce_scatter64(a, lane) + b_own;
    const float v_own = av * h_own - fmaxf(pre, 0.f);
    st_f32_sc01(v_buf + hidx, v_own);
    vm_wait0();
    group_barrier(flags + t * 16 + rt);  // group's v complete at MALL

    // ---- stage v rows ----
    {
      const float4* src = (const float4*)(v_buf + (size_t)rg0 * Hn) + tid;
      float4 r[8];
      float4* dst = (float4*)sm;
      ldx8_sc01(src, r);
#pragma unroll
      for (int u = 0; u < 8; u++) dst[tid + 256 * u] = r[u];
      ldx8_sc01(src + 2048, r);
#pragma unroll
      for (int u = 0; u < 8; u++) dst[tid + 2048 + 256 * u] = r[u];
    }
    __syncthreads();

    // ---- phase 2: u = v @ Wh^T ----
#pragma unroll
    for (int i = 0; i < 64; i++) a[i] = 0.f;
    {
      const float* Wb = WTp + ((size_t)ct * Hn << 4) + c0w;
#pragma unroll
      for (int j = 0; j < 4; j++) {
        const int kb = 4 * lane + 256 * j;
        float4 v4[8];
#pragma unroll
        for (int i = 0; i < 8; i++)
          v4[i] = *(const float4*)(sm + (r0w + i) * Hn + kb);
#pragma unroll
        for (int q = 0; q < 4; q++) {
          const float* wr = Wb + ((size_t)(kb + q) << 4);
          const float4 wA = *(const float4*)(wr);
          const float4 wB = *(const float4*)(wr + 4);
#pragma unroll
          for (int i = 0; i < 8; i++) {
            const float vv = ((const float*)&v4[i])[q];
            FMA8(vv, wA, wB, i * 8);
          }
        }
      }
    }
    const float uu = reduce_scatter64(a, lane);
    const float phi = av * h_own - v_own;  // exact reconstruction
    const float hn = h_own - LR * (av * v_own - (phi > 0.f ? uu : 0.f));
    h_own = hn;
    st_f32_sc01(h_cur + hidx, hn);  // for next step's stagers
    vm_wait0();
    if (t == Tn - 1) hfin[hidx] = hn;  // kernel-end release flushes
    hn_s[rl][cl] = hn;
    __syncthreads();
    if (tid < 160) {  // fused FC partial over this block's 16 cols
      float s = 0.f;
#pragma unroll
      for (int jj = 0; jj < 16; jj++) s += hn_s[rr][jj] * fc_r[jj];
      atomicAdd(&out[((size_t)(rg0 + rr) * Tn + t) * Cn + cc], s);
    }
    group_barrier(flags + t * 16 + 8 + rt);  // group's h complete at MALL
  }
}

extern "C" void kernel_launch(void* const* d_in, const int* in_sizes, int n_in,
                              void* d_out, int out_size, void* d_ws, size_t ws_size,
                              hipStream_t stream) {
  const float* X      = (const float*)d_in[0];
  const float* hidden = (const float*)d_in[1];
  const float* alpha  = (const float*)d_in[2];
  const float* bias   = (const float*)d_in[3];
  const float* Wh     = (const float*)d_in[4];
  const float* Wx     = (const float*)d_in[5];
  const float* fc_w   = (const float*)d_in[6];
  const float* fc_b   = (const float*)d_in[7];
  float* out  = (float*)d_out;
  float* hfin = out + (size_t)Bsz * Tn * Cn;

  char* ws = (char*)d_ws;
  float* Whp   = (float*)(ws);                 // 4 MB
  float* WTp   = (float*)(ws + (4u << 20));    // 4 MB
  float* Wxp   = (float*)(ws + (8u << 20));    // 1 MB
  float* h_cur = (float*)(ws + (9u << 20));    // 512 KB
  float* v_buf = (float*)(ws + (9u << 20) + (512u << 10));  // 512 KB
  int*   flags = (int*)(ws + (10u << 20));     // 16 KB

  const int lds = 16 * Hn * 4;  // 64 KB
  hipFuncSetAttribute((const void*)k_persist,
                      hipFuncAttributeMaxDynamicSharedMemorySize, lds);

  k_pack<<<4096, 256, 0, stream>>>(Wh, Wx, Whp, Wxp);
  k_transpack<<<dim3(32, 32), 256, 0, stream>>>(Wh, WTp);
  k_init<<<1280, 256, 0, stream>>>(out, fc_b, h_cur, hidden, flags);
  k_persist<<<512, 256, lds, stream>>>(X, h_cur, v_buf, Whp, Wxp, WTp, bias,
                                       alpha, fc_w, out, hfin, flags);
}

// Round 6
// 91090.405 us; speedup vs baseline: 1.0530x; 1.0530x over previous
//
#include <hip/hip_runtime.h>

// ODE_Vanilla scan: B=128, T=256, I=256, H=1024, C=10, fp32.
// R6 = R5 (one persistent kernel, MALL-coherent h/v exchange via sc0 sc1,
// group barriers) with the ACTUAL R3/R5 killer fixed: VGPR_Count=128 forced
// spilling of the 64-accumulator array -> ~350 GB scratch HBM traffic.
// Fix: amdgpu_waves_per_eu(2,2) (256-VGPR budget; 2 blocks/CU is the LDS
// limit anyway), drop fc_r preload, 4-wide asm loader (lower peak pressure).
// Barrier: 16 monotonic counters (phase,rt) on separate 128-B lines; wait
// for count >= 64*(t+1); no resets; bounded spin as escape hatch.

constexpr int Bsz = 128, Tn = 256, In = 256, Hn = 1024, Cn = 10;
constexpr float LR = 0.001f;

// ---- pack Wh, Wx into [ct][k][16 cols] contiguous slices
__global__ __launch_bounds__(256) void k_pack(const float* __restrict__ Wh,
                                              const float* __restrict__ Wx,
                                              float* __restrict__ Whp,
                                              float* __restrict__ Wxp) {
  const int g = blockIdx.x * 256 + threadIdx.x;
  {
    const int k = g >> 10, c = g & 1023;
    Whp[(((size_t)(c >> 4) * Hn + k) << 4) + (c & 15)] = Wh[g];
  }
  if (g < In * Hn) {
    const int k = g >> 10, c = g & 1023;
    Wxp[(((size_t)(c >> 4) * In + k) << 4) + (c & 15)] = Wx[g];
  }
}

// ---- Wh^T packed into [ct][k][16 cols]
__global__ __launch_bounds__(256) void k_transpack(const float* __restrict__ W,
                                                   float* __restrict__ WTp) {
  __shared__ float tile[32][33];
  const int bx = blockIdx.x * 32, by = blockIdx.y * 32;
  const int tx = threadIdx.x & 31, ty = threadIdx.x >> 5;
#pragma unroll
  for (int dy = 0; dy < 32; dy += 8)
    tile[ty + dy][tx] = W[(size_t)(by + ty + dy) * Hn + bx + tx];
  __syncthreads();
#pragma unroll
  for (int dy = 0; dy < 32; dy += 8) {
    const int k = bx + ty + dy, c = by + tx;
    WTp[(((size_t)(c >> 4) * Hn + k) << 4) + (c & 15)] = tile[tx][ty + dy];
  }
}

__global__ __launch_bounds__(256) void k_init(float* __restrict__ out,
                                              const float* __restrict__ fc_b,
                                              float* __restrict__ h_cur,
                                              const float* __restrict__ hidden,
                                              int* __restrict__ bar) {
  const int i = blockIdx.x * blockDim.x + threadIdx.x;
  if (i < Bsz * Tn * Cn) out[i] = fc_b[i % Cn];
  if (i < Bsz * Hn) h_cur[i] = hidden[i];
  if (i < 512) bar[i] = 0;
}

// ---- MALL-coherent (cross-XCD) helpers: bypass L1+L2 via sc0 sc1
__device__ __forceinline__ void ldx4_sc01(const float4* b, float4 (&r)[4]) {
  asm volatile(
      "global_load_dwordx4 %0, %4, off sc0 sc1\n\t"
      "global_load_dwordx4 %1, %5, off sc0 sc1\n\t"
      "global_load_dwordx4 %2, %6, off sc0 sc1\n\t"
      "global_load_dwordx4 %3, %7, off sc0 sc1\n\t"
      "s_waitcnt vmcnt(0)"
      : "=&v"(r[0]), "=&v"(r[1]), "=&v"(r[2]), "=&v"(r[3])
      : "v"(b), "v"(b + 256), "v"(b + 512), "v"(b + 768)
      : "memory");
}
__device__ __forceinline__ void st_f32_sc01(float* p, float v) {
  asm volatile("global_store_dword %0, %1, off sc0 sc1" ::"v"(p), "v"(v)
               : "memory");
}
__device__ __forceinline__ void vm_wait0() {
  asm volatile("s_waitcnt vmcnt(0)" ::: "memory");
}

// ---- group barrier: 64 blocks of one rt-group arrive on one monotonic
// counter; wait until count >= tgt = 64*(t+1). No fences (data goes through
// MALL). Bounded spin -> visible failure instead of a hang.
__device__ __forceinline__ void group_barrier(int* flag, int tgt) {
  __syncthreads();
  if (threadIdx.x == 0) {
    __hip_atomic_fetch_add(flag, 1, __ATOMIC_RELAXED, __HIP_MEMORY_SCOPE_AGENT);
    int it = 0;
    while (__hip_atomic_load(flag, __ATOMIC_RELAXED,
                             __HIP_MEMORY_SCOPE_AGENT) < tgt) {
      __builtin_amdgcn_s_sleep(2);
      if (++it > 8000000) break;  // escape hatch
    }
  }
  __syncthreads();
}

// reduce-scatter over 64 lanes: lane l ends with full sum of a[l]
__device__ __forceinline__ float reduce_scatter64(float (&a)[64], int lane) {
#pragma unroll
  for (int m = 32; m >= 1; m >>= 1) {
#pragma unroll
    for (int i = 0; i < m; i++) {
      const float send = (lane & m) ? a[i] : a[i + m];
      const float keep = (lane & m) ? a[i + m] : a[i];
      a[i] = keep + __shfl_xor(send, m, 64);
    }
  }
  return a[0];
}

#define FMA8(s, wA, wB, base)                          \
  a[(base) + 0] = fmaf((s), (wA).x, a[(base) + 0]);    \
  a[(base) + 1] = fmaf((s), (wA).y, a[(base) + 1]);    \
  a[(base) + 2] = fmaf((s), (wA).z, a[(base) + 2]);    \
  a[(base) + 3] = fmaf((s), (wA).w, a[(base) + 3]);    \
  a[(base) + 4] = fmaf((s), (wB).x, a[(base) + 4]);    \
  a[(base) + 5] = fmaf((s), (wB).y, a[(base) + 5]);    \
  a[(base) + 6] = fmaf((s), (wB).z, a[(base) + 6]);    \
  a[(base) + 7] = fmaf((s), (wB).w, a[(base) + 7]);

// grid 512 = rt(8) x ct(64); 256 thr = 4 waves; lane = 64-way k-split.
// Thread owns output element (rg0+r0w+(lane>>3), c_blk+c0w+(lane&7)).
__global__ __attribute__((amdgpu_flat_work_group_size(256, 256),
                          amdgpu_waves_per_eu(2, 2))) void k_persist(
    const float* __restrict__ X, float* __restrict__ h_cur,
    float* __restrict__ v_buf, const float* __restrict__ Whp,
    const float* __restrict__ Wxp, const float* __restrict__ WTp,
    const float* __restrict__ bias, const float* __restrict__ alpha,
    const float* __restrict__ fc_w, float* __restrict__ out,
    float* __restrict__ hfin, int* __restrict__ bar) {
  extern __shared__ float sm[];  // 16 rows x 1024 = 64 KB
  __shared__ float hn_s[16][16];
  const int tid = threadIdx.x, lane = tid & 63, w = tid >> 6;
  const int rt = blockIdx.x >> 6, ct = blockIdx.x & 63;
  const int rg0 = rt * 16, c_blk = ct * 16;
  const int r0w = (w >> 1) * 8, c0w = (w & 1) * 8;
  const int rl = r0w + (lane >> 3), cl = c0w + (lane & 7);
  const int cg = c_blk + cl;
  const size_t hidx = (size_t)(rg0 + rl) * Hn + cg;
  const float av = alpha[0];
  const float b_own = bias[cg];
  float h_own = h_cur[hidx];  // k_init wrote it; dispatch-boundary coherent
  int* bar_v = bar + rt * 32;         // phase-1 counter (own 128-B line)
  int* bar_h = bar + (8 + rt) * 32;   // phase-2 counter
  const int rr = tid / 10, cc = tid % 10;

  for (int t = 0; t < Tn; t++) {
    // ---- stage h rows via MALL-coherent loads ----
    {
      const float4* src = (const float4*)(h_cur + (size_t)rg0 * Hn) + tid;
      float4* dst = ((float4*)sm) + tid;
      float4 r[4];
#pragma unroll
      for (int ch = 0; ch < 4; ch++) {
        ldx4_sc01(src + 1024 * ch, r);
        dst[1024 * ch] = r[0];
        dst[1024 * ch + 256] = r[1];
        dst[1024 * ch + 512] = r[2];
        dst[1024 * ch + 768] = r[3];
      }
    }
    __syncthreads();

    // ---- phase 1: pre = h@Wh + x@Wx ----
    float a[64];
#pragma unroll
    for (int i = 0; i < 64; i++) a[i] = 0.f;
    {
      const float* Wb = Whp + ((size_t)ct * Hn << 4) + c0w;
#pragma unroll
      for (int j = 0; j < 4; j++) {
        const int kb = 4 * lane + 256 * j;
        float4 h4[8];
#pragma unroll
        for (int i = 0; i < 8; i++)
          h4[i] = *(const float4*)(sm + (r0w + i) * Hn + kb);
#pragma unroll
        for (int q = 0; q < 4; q++) {
          const float* wr = Wb + ((size_t)(kb + q) << 4);
          const float4 wA = *(const float4*)(wr);
          const float4 wB = *(const float4*)(wr + 4);
#pragma unroll
          for (int i = 0; i < 8; i++) {
            const float hv = ((const float*)&h4[i])[q];
            FMA8(hv, wA, wB, i * 8);
          }
        }
      }
    }
    {
      const int kb = 4 * lane;
      float4 x4[8];
#pragma unroll
      for (int i = 0; i < 8; i++)
        x4[i] = *(const float4*)(X + ((size_t)(rg0 + r0w + i) * Tn + t) * In + kb);
      const float* Wb = Wxp + ((size_t)ct * In << 4) + c0w;
#pragma unroll
      for (int q = 0; q < 4; q++) {
        const float* wr = Wb + ((size_t)(kb + q) << 4);
        const float4 wA = *(const float4*)(wr);
        const float4 wB = *(const float4*)(wr + 4);
#pragma unroll
        for (int i = 0; i < 8; i++) {
          const float xv = ((const float*)&x4[i])[q];
          FMA8(xv, wA, wB, i * 8);
        }
      }
    }
    const float pre = reduce_scatter64(a, lane) + b_own;
    const float v_own = av * h_own - fmaxf(pre, 0.f);
    st_f32_sc01(v_buf + hidx, v_own);
    vm_wait0();
    group_barrier(bar_v, (t + 1) << 6);  // group's v complete at MALL

    // ---- stage v rows ----
    {
      const float4* src = (const float4*)(v_buf + (size_t)rg0 * Hn) + tid;
      float4* dst = ((float4*)sm) + tid;
      float4 r[4];
#pragma unroll
      for (int ch = 0; ch < 4; ch++) {
        ldx4_sc01(src + 1024 * ch, r);
        dst[1024 * ch] = r[0];
        dst[1024 * ch + 256] = r[1];
        dst[1024 * ch + 512] = r[2];
        dst[1024 * ch + 768] = r[3];
      }
    }
    __syncthreads();

    // ---- phase 2: u = v @ Wh^T ----
#pragma unroll
    for (int i = 0; i < 64; i++) a[i] = 0.f;
    {
      const float* Wb = WTp + ((size_t)ct * Hn << 4) + c0w;
#pragma unroll
      for (int j = 0; j < 4; j++) {
        const int kb = 4 * lane + 256 * j;
        float4 v4[8];
#pragma unroll
        for (int i = 0; i < 8; i++)
          v4[i] = *(const float4*)(sm + (r0w + i) * Hn + kb);
#pragma unroll
        for (int q = 0; q < 4; q++) {
          const float* wr = Wb + ((size_t)(kb + q) << 4);
          const float4 wA = *(const float4*)(wr);
          const float4 wB = *(const float4*)(wr + 4);
#pragma unroll
          for (int i = 0; i < 8; i++) {
            const float vv = ((const float*)&v4[i])[q];
            FMA8(vv, wA, wB, i * 8);
          }
        }
      }
    }
    const float uu = reduce_scatter64(a, lane);
    const float phi = av * h_own - v_own;  // exact reconstruction
    const float hn = h_own - LR * (av * v_own - (phi > 0.f ? uu : 0.f));
    h_own = hn;
    st_f32_sc01(h_cur + hidx, hn);  // next step's stagers read via MALL
    vm_wait0();
    if (t == Tn - 1) hfin[hidx] = hn;  // kernel-end release flushes
    hn_s[rl][cl] = hn;
    __syncthreads();
    if (tid < 160) {  // fused FC partial over this block's 16 cols
      float s = 0.f;
#pragma unroll
      for (int jj = 0; jj < 16; jj++)
        s += hn_s[rr][jj] * fc_w[(size_t)(c_blk + jj) * Cn + cc];
      atomicAdd(&out[((size_t)(rg0 + rr) * Tn + t) * Cn + cc], s);
    }
    group_barrier(bar_h, (t + 1) << 6);  // group's h complete at MALL
  }
}

extern "C" void kernel_launch(void* const* d_in, const int* in_sizes, int n_in,
                              void* d_out, int out_size, void* d_ws, size_t ws_size,
                              hipStream_t stream) {
  const float* X      = (const float*)d_in[0];
  const float* hidden = (const float*)d_in[1];
  const float* alpha  = (const float*)d_in[2];
  const float* bias   = (const float*)d_in[3];
  const float* Wh     = (const float*)d_in[4];
  const float* Wx     = (const float*)d_in[5];
  const float* fc_w   = (const float*)d_in[6];
  const float* fc_b   = (const float*)d_in[7];
  float* out  = (float*)d_out;
  float* hfin = out + (size_t)Bsz * Tn * Cn;

  char* ws = (char*)d_ws;
  float* Whp   = (float*)(ws);                 // 4 MB
  float* WTp   = (float*)(ws + (4u << 20));    // 4 MB
  float* Wxp   = (float*)(ws + (8u << 20));    // 1 MB
  float* h_cur = (float*)(ws + (9u << 20));    // 512 KB
  float* v_buf = (float*)(ws + (9u << 20) + (512u << 10));  // 512 KB
  int*   bar   = (int*)(ws + (10u << 20));     // 2 KB (16 counters x 128 B)

  const int lds = 16 * Hn * 4;  // 64 KB
  hipFuncSetAttribute((const void*)k_persist,
                      hipFuncAttributeMaxDynamicSharedMemorySize, lds);

  k_pack<<<4096, 256, 0, stream>>>(Wh, Wx, Whp, Wxp);
  k_transpack<<<dim3(32, 32), 256, 0, stream>>>(Wh, WTp);
  k_init<<<1280, 256, 0, stream>>>(out, fc_b, h_cur, hidden, bar);
  k_persist<<<512, 256, lds, stream>>>(X, h_cur, v_buf, Whp, Wxp, WTp, bias,
                                       alpha, fc_w, out, hfin, bar);
}

// Round 7
// 22593.918 us; speedup vs baseline: 4.2452x; 4.0316x over previous
//
#include <hip/hip_runtime.h>

// ODE_Vanilla scan: B=128, T=256, I=256, H=1024, C=10, fp32.
// R7 = R6 with the spill ACTUALLY killed. R5/R6 evidence: VGPR_Count pinned
// at 128 regardless of waves_per_eu/launch_bounds attributes; a[64]
// accumulator array spilled -> 270 GB scratch writes/dispatch. Fix: shrink
// the per-thread tile instead of fighting the allocator. Half-wave row
// split: lane = 32*hh + s; half hh owns 4 rows of the wave's 8x8 tile;
// s = 32-way k-split (32 k's/lane, each output = 32 lanes x 32 k = 1024).
// Per-thread: a[32], h4[4] -> ~90 VGPR demand, fits the 128 cap.
// 5-stage width-32 butterfly lands lane l on output (l>>3, l&7) -- same
// ownership map as R4/R5/R6, epilogue unchanged.
// Persistent kernel keeps weights L2-resident across all 256 steps (multi-
// kernel pays ~32MB L3 re-stream per dispatch boundary = the 21us floor).

constexpr int Bsz = 128, Tn = 256, In = 256, Hn = 1024, Cn = 10;
constexpr float LR = 0.001f;

// ---- pack Wh, Wx into [ct][k][16 cols] contiguous slices
__global__ __launch_bounds__(256) void k_pack(const float* __restrict__ Wh,
                                              const float* __restrict__ Wx,
                                              float* __restrict__ Whp,
                                              float* __restrict__ Wxp) {
  const int g = blockIdx.x * 256 + threadIdx.x;
  {
    const int k = g >> 10, c = g & 1023;
    Whp[(((size_t)(c >> 4) * Hn + k) << 4) + (c & 15)] = Wh[g];
  }
  if (g < In * Hn) {
    const int k = g >> 10, c = g & 1023;
    Wxp[(((size_t)(c >> 4) * In + k) << 4) + (c & 15)] = Wx[g];
  }
}

// ---- Wh^T packed into [ct][k][16 cols]
__global__ __launch_bounds__(256) void k_transpack(const float* __restrict__ W,
                                                   float* __restrict__ WTp) {
  __shared__ float tile[32][33];
  const int bx = blockIdx.x * 32, by = blockIdx.y * 32;
  const int tx = threadIdx.x & 31, ty = threadIdx.x >> 5;
#pragma unroll
  for (int dy = 0; dy < 32; dy += 8)
    tile[ty + dy][tx] = W[(size_t)(by + ty + dy) * Hn + bx + tx];
  __syncthreads();
#pragma unroll
  for (int dy = 0; dy < 32; dy += 8) {
    const int k = bx + ty + dy, c = by + tx;
    WTp[(((size_t)(c >> 4) * Hn + k) << 4) + (c & 15)] = tile[tx][ty + dy];
  }
}

__global__ __launch_bounds__(256) void k_init(float* __restrict__ out,
                                              const float* __restrict__ fc_b,
                                              float* __restrict__ h_cur,
                                              const float* __restrict__ hidden,
                                              int* __restrict__ bar) {
  const int i = blockIdx.x * blockDim.x + threadIdx.x;
  if (i < Bsz * Tn * Cn) out[i] = fc_b[i % Cn];
  if (i < Bsz * Hn) h_cur[i] = hidden[i];
  if (i < 512) bar[i] = 0;
}

// ---- MALL-coherent (cross-XCD) helpers: bypass L1+L2 via sc0 sc1
__device__ __forceinline__ void ldx4_sc01(const float4* b, float4 (&r)[4]) {
  asm volatile(
      "global_load_dwordx4 %0, %4, off sc0 sc1\n\t"
      "global_load_dwordx4 %1, %5, off sc0 sc1\n\t"
      "global_load_dwordx4 %2, %6, off sc0 sc1\n\t"
      "global_load_dwordx4 %3, %7, off sc0 sc1\n\t"
      "s_waitcnt vmcnt(0)"
      : "=&v"(r[0]), "=&v"(r[1]), "=&v"(r[2]), "=&v"(r[3])
      : "v"(b), "v"(b + 256), "v"(b + 512), "v"(b + 768)
      : "memory");
}
__device__ __forceinline__ void st_f32_sc01(float* p, float v) {
  asm volatile("global_store_dword %0, %1, off sc0 sc1" ::"v"(p), "v"(v)
               : "memory");
}
__device__ __forceinline__ void vm_wait0() {
  asm volatile("s_waitcnt vmcnt(0)" ::: "memory");
}

// ---- group barrier: 64 blocks of one rt-group on one monotonic counter;
// wait until count >= 64*(t_phase+1). No fences (data goes through MALL).
__device__ __forceinline__ void group_barrier(int* flag, int tgt) {
  __syncthreads();
  if (threadIdx.x == 0) {
    __hip_atomic_fetch_add(flag, 1, __ATOMIC_RELAXED, __HIP_MEMORY_SCOPE_AGENT);
    int it = 0;
    while (__hip_atomic_load(flag, __ATOMIC_RELAXED,
                             __HIP_MEMORY_SCOPE_AGENT) < tgt) {
      __builtin_amdgcn_s_sleep(2);
      if (++it > 8000000) break;  // escape hatch: fail visibly, don't hang
    }
  }
  __syncthreads();
}

// 5-stage width-32 reduce-scatter: lane l ends with the full (32-lane
// half-group) sum of a[l&31]. Masks <32 keep exchanges within each half.
__device__ __forceinline__ float reduce_scatter32(float (&a)[32], int lane) {
#pragma unroll
  for (int m = 16; m >= 1; m >>= 1) {
#pragma unroll
    for (int i = 0; i < m; i++) {
      const float send = (lane & m) ? a[i] : a[i + m];
      const float keep = (lane & m) ? a[i + m] : a[i];
      a[i] = keep + __shfl_xor(send, m, 64);
    }
  }
  return a[0];
}

#define FMA8(s, wA, wB, base)                          \
  a[(base) + 0] = fmaf((s), (wA).x, a[(base) + 0]);    \
  a[(base) + 1] = fmaf((s), (wA).y, a[(base) + 1]);    \
  a[(base) + 2] = fmaf((s), (wA).z, a[(base) + 2]);    \
  a[(base) + 3] = fmaf((s), (wA).w, a[(base) + 3]);    \
  a[(base) + 4] = fmaf((s), (wB).x, a[(base) + 4]);    \
  a[(base) + 5] = fmaf((s), (wB).y, a[(base) + 5]);    \
  a[(base) + 6] = fmaf((s), (wB).z, a[(base) + 6]);    \
  a[(base) + 7] = fmaf((s), (wB).w, a[(base) + 7]);

// grid 512 = rt(8) x ct(64); 256 thr = 4 waves (wave tile 8r x 8c).
// lane = 32*hh + s: half hh computes rows r0w+hh*4..+3; s = 32-way k-split.
__global__ __launch_bounds__(256, 2) void k_persist(
    const float* __restrict__ X, float* __restrict__ h_cur,
    float* __restrict__ v_buf, const float* __restrict__ Whp,
    const float* __restrict__ Wxp, const float* __restrict__ WTp,
    const float* __restrict__ bias, const float* __restrict__ alpha,
    const float* __restrict__ fc_w, float* __restrict__ out,
    float* __restrict__ hfin, int* __restrict__ bar) {
  extern __shared__ float sm[];  // 16 rows x 1024 = 64 KB
  __shared__ float hn_s[16][16];
  const int tid = threadIdx.x, lane = tid & 63, w = tid >> 6;
  const int rt = blockIdx.x >> 6, ct = blockIdx.x & 63;
  const int rg0 = rt * 16, c_blk = ct * 16;
  const int r0w = (w >> 1) * 8, c0w = (w & 1) * 8;
  const int s = lane & 31, hh = lane >> 5;
  const int rb = r0w + hh * 4;              // this thread's 4-row base
  const int rl = r0w + (lane >> 3), cl = c0w + (lane & 7);  // owned output
  const int cg = c_blk + cl;
  const size_t hidx = (size_t)(rg0 + rl) * Hn + cg;
  const float av = alpha[0];
  const float b_own = bias[cg];
  float h_own = h_cur[hidx];  // k_init wrote it; dispatch-boundary coherent
  int* bar_v = bar + rt * 32;        // phase-1 counter (own 128-B line)
  int* bar_h = bar + (8 + rt) * 32;  // phase-2 counter
  const int rr = tid / 10, cc = tid % 10;

  for (int t = 0; t < Tn; t++) {
    // ---- stage h rows via MALL-coherent loads ----
    {
      const float4* src = (const float4*)(h_cur + (size_t)rg0 * Hn) + tid;
      float4* dst = ((float4*)sm) + tid;
      float4 r[4];
#pragma unroll
      for (int ch = 0; ch < 4; ch++) {
        ldx4_sc01(src + 1024 * ch, r);
        dst[1024 * ch] = r[0];
        dst[1024 * ch + 256] = r[1];
        dst[1024 * ch + 512] = r[2];
        dst[1024 * ch + 768] = r[3];
      }
    }
    __syncthreads();

    // ---- phase 1: pre = h@Wh + x@Wx (half-wave rows, 32-way k-split) ----
    float a[32];
#pragma unroll
    for (int i = 0; i < 32; i++) a[i] = 0.f;
    {
      const float* Wb = Whp + ((size_t)ct * Hn << 4) + c0w;
#pragma unroll
      for (int j = 0; j < 8; j++) {
        const int kb = 4 * s + 128 * j;
        float4 h4[4];
#pragma unroll
        for (int i = 0; i < 4; i++)
          h4[i] = *(const float4*)(sm + (rb + i) * Hn + kb);
#pragma unroll
        for (int q = 0; q < 4; q++) {
          const float* wr = Wb + ((size_t)(kb + q) << 4);
          const float4 wA = *(const float4*)(wr);
          const float4 wB = *(const float4*)(wr + 4);
#pragma unroll
          for (int i = 0; i < 4; i++) {
            const float hv = ((const float*)&h4[i])[q];
            FMA8(hv, wA, wB, i * 8);
          }
        }
      }
    }
    {  // x_t @ Wx: per half, k = 4s + 128*jj + q covers [0,256)
      const float* Wb = Wxp + ((size_t)ct * In << 4) + c0w;
#pragma unroll
      for (int jj = 0; jj < 2; jj++) {
        const int kb = 4 * s + 128 * jj;
        float4 x4[4];
#pragma unroll
        for (int i = 0; i < 4; i++)
          x4[i] = *(const float4*)(X + ((size_t)(rg0 + rb + i) * Tn + t) * In + kb);
#pragma unroll
        for (int q = 0; q < 4; q++) {
          const float* wr = Wb + ((size_t)(kb + q) << 4);
          const float4 wA = *(const float4*)(wr);
          const float4 wB = *(const float4*)(wr + 4);
#pragma unroll
          for (int i = 0; i < 4; i++) {
            const float xv = ((const float*)&x4[i])[q];
            FMA8(xv, wA, wB, i * 8);
          }
        }
      }
    }
    const float pre = reduce_scatter32(a, lane) + b_own;
    const float v_own = av * h_own - fmaxf(pre, 0.f);
    st_f32_sc01(v_buf + hidx, v_own);
    vm_wait0();
    group_barrier(bar_v, (t + 1) << 6);  // group's v complete at MALL

    // ---- stage v rows ----
    {
      const float4* src = (const float4*)(v_buf + (size_t)rg0 * Hn) + tid;
      float4* dst = ((float4*)sm) + tid;
      float4 r[4];
#pragma unroll
      for (int ch = 0; ch < 4; ch++) {
        ldx4_sc01(src + 1024 * ch, r);
        dst[1024 * ch] = r[0];
        dst[1024 * ch + 256] = r[1];
        dst[1024 * ch + 512] = r[2];
        dst[1024 * ch + 768] = r[3];
      }
    }
    __syncthreads();

    // ---- phase 2: u = v @ Wh^T ----
#pragma unroll
    for (int i = 0; i < 32; i++) a[i] = 0.f;
    {
      const float* Wb = WTp + ((size_t)ct * Hn << 4) + c0w;
#pragma unroll
      for (int j = 0; j < 8; j++) {
        const int kb = 4 * s + 128 * j;
        float4 v4[4];
#pragma unroll
        for (int i = 0; i < 4; i++)
          v4[i] = *(const float4*)(sm + (rb + i) * Hn + kb);
#pragma unroll
        for (int q = 0; q < 4; q++) {
          const float* wr = Wb + ((size_t)(kb + q) << 4);
          const float4 wA = *(const float4*)(wr);
          const float4 wB = *(const float4*)(wr + 4);
#pragma unroll
          for (int i = 0; i < 4; i++) {
            const float vv = ((const float*)&v4[i])[q];
            FMA8(vv, wA, wB, i * 8);
          }
        }
      }
    }
    const float uu = reduce_scatter32(a, lane);
    const float phi = av * h_own - v_own;  // exact reconstruction
    const float hn = h_own - LR * (av * v_own - (phi > 0.f ? uu : 0.f));
    h_own = hn;
    st_f32_sc01(h_cur + hidx, hn);  // next step's stagers read via MALL
    vm_wait0();
    if (t == Tn - 1) hfin[hidx] = hn;  // kernel-end release flushes
    hn_s[rl][cl] = hn;
    __syncthreads();
    if (tid < 160) {  // fused FC partial over this block's 16 cols
      float ssum = 0.f;
#pragma unroll
      for (int jj = 0; jj < 16; jj++)
        ssum += hn_s[rr][jj] * fc_w[(size_t)(c_blk + jj) * Cn + cc];
      atomicAdd(&out[((size_t)(rg0 + rr) * Tn + t) * Cn + cc], ssum);
    }
    group_barrier(bar_h, (t + 1) << 6);  // group's h complete at MALL
  }
}

extern "C" void kernel_launch(void* const* d_in, const int* in_sizes, int n_in,
                              void* d_out, int out_size, void* d_ws, size_t ws_size,
                              hipStream_t stream) {
  const float* X      = (const float*)d_in[0];
  const float* hidden = (const float*)d_in[1];
  const float* alpha  = (const float*)d_in[2];
  const float* bias   = (const float*)d_in[3];
  const float* Wh     = (const float*)d_in[4];
  const float* Wx     = (const float*)d_in[5];
  const float* fc_w   = (const float*)d_in[6];
  const float* fc_b   = (const float*)d_in[7];
  float* out  = (float*)d_out;
  float* hfin = out + (size_t)Bsz * Tn * Cn;

  char* ws = (char*)d_ws;
  float* Whp   = (float*)(ws);                 // 4 MB
  float* WTp   = (float*)(ws + (4u << 20));    // 4 MB
  float* Wxp   = (float*)(ws + (8u << 20));    // 1 MB
  float* h_cur = (float*)(ws + (9u << 20));    // 512 KB
  float* v_buf = (float*)(ws + (9u << 20) + (512u << 10));  // 512 KB
  int*   bar   = (int*)(ws + (10u << 20));     // 2 KB (16 counters x 128 B)

  const int lds = 16 * Hn * 4;  // 64 KB
  hipFuncSetAttribute((const void*)k_persist,
                      hipFuncAttributeMaxDynamicSharedMemorySize, lds);

  k_pack<<<4096, 256, 0, stream>>>(Wh, Wx, Whp, Wxp);
  k_transpack<<<dim3(32, 32), 256, 0, stream>>>(Wh, WTp);
  k_init<<<1280, 256, 0, stream>>>(out, fc_b, h_cur, hidden, bar);
  k_persist<<<512, 256, lds, stream>>>(X, h_cur, v_buf, Whp, Wxp, WTp, bias,
                                       alpha, fc_w, out, hfin, bar);
}